// Round 1
// baseline (168.356 us; speedup 1.0000x reference)
//
#include <hip/hip_runtime.h>
#include <math.h>

#define SEQ 4096
#define NH  8
#define DIM 64
// 32 (n,h) pairs total: n=4, h=8

__device__ __forceinline__ float elu1(float x) {
    // jax.nn.elu(x)+1 = x+1 (x>0) else exp(x)
    return x > 0.0f ? x + 1.0f : __expf(x);
}

// ---------------- Phase 1: partial KV (64x64) + partial Ksum per (n,h,chunk) ----------------
__global__ __launch_bounds__(256) void k_phase1(const float* __restrict__ Kin,
                                                const float* __restrict__ Vin,
                                                float* __restrict__ pKV,
                                                float* __restrict__ pKs,
                                                int NC, int sLen) {
    const int nh = blockIdx.x / NC;
    const int ck = blockIdx.x % NC;
    const int n  = nh >> 3, h = nh & 7;
    const int t  = threadIdx.x;
    const int r  = t >> 4;          // staging row 0..15
    const int c  = (t & 15) * 4;    // staging col (x4)
    const int d0 = (t >> 4) * 4;    // owned d block
    const int v0 = (t & 15) * 4;    // owned v block

    __shared__ __align__(16) float kf[16][64];
    __shared__ __align__(16) float vv[16][64];

    float acc[4][4];
#pragma unroll
    for (int i = 0; i < 4; i++)
#pragma unroll
        for (int j = 0; j < 4; j++) acc[i][j] = 0.0f;
    float ks[4] = {0.0f, 0.0f, 0.0f, 0.0f};

    const int s0 = ck * sLen;
    const int iters = sLen >> 4;
    for (int it = 0; it < iters; ++it) {
        const int s = s0 + it * 16 + r;
        const size_t g = ((size_t)(n * SEQ + s) * NH + h) * DIM + c;
        float4 k4 = *(const float4*)(Kin + g);
        float4 v4 = *(const float4*)(Vin + g);
        float4 f4;
        f4.x = elu1(k4.x); f4.y = elu1(k4.y); f4.z = elu1(k4.z); f4.w = elu1(k4.w);
        ks[0] += f4.x; ks[1] += f4.y; ks[2] += f4.z; ks[3] += f4.w;
        *(float4*)&kf[r][c] = f4;
        *(float4*)&vv[r][c] = v4;
        __syncthreads();
#pragma unroll
        for (int ss = 0; ss < 16; ++ss) {
            float4 a4 = *(const float4*)&kf[ss][d0];
            float4 b4 = *(const float4*)&vv[ss][v0];
            float a[4] = {a4.x, a4.y, a4.z, a4.w};
            float b[4] = {b4.x, b4.y, b4.z, b4.w};
#pragma unroll
            for (int i = 0; i < 4; i++)
#pragma unroll
                for (int j = 0; j < 4; j++)
                    acc[i][j] = fmaf(a[i], b[j], acc[i][j]);
        }
        __syncthreads();
    }

    // store partial KV: layout pKV[(ck*32+nh)][d][v]
    float* dst = pKV + ((size_t)ck * 32 + nh) * 4096;
#pragma unroll
    for (int i = 0; i < 4; i++) {
        float4 o;
        o.x = acc[i][0]; o.y = acc[i][1]; o.z = acc[i][2]; o.w = acc[i][3];
        *(float4*)(dst + (d0 + i) * 64 + v0) = o;
    }

    // Ksum reduce via LDS (reuse kf; all compute-loop reads are behind the last sync)
    *(float4*)&kf[r][c] = make_float4(ks[0], ks[1], ks[2], ks[3]);
    __syncthreads();
    if (t < 64) {
        float s = 0.0f;
#pragma unroll
        for (int rr = 0; rr < 16; ++rr) s += kf[rr][t];
        pKs[((size_t)ck * 32 + nh) * 64 + t] = s;
    }
}

// ---------------- Reduce partials -> final KV, Ksum ----------------
__global__ __launch_bounds__(256) void k_reduce(const float* __restrict__ pKV,
                                                const float* __restrict__ pKs,
                                                float* __restrict__ KVf,
                                                float* __restrict__ Ksf,
                                                int NC) {
    const int nh = blockIdx.x;
    const int t = threadIdx.x;
    for (int e = t; e < 1024; e += 256) {   // 1024 float4 = 4096 floats
        float4 s = make_float4(0.f, 0.f, 0.f, 0.f);
        for (int c2 = 0; c2 < NC; ++c2) {
            float4 p = *(const float4*)(pKV + ((size_t)c2 * 32 + nh) * 4096 + (size_t)e * 4);
            s.x += p.x; s.y += p.y; s.z += p.z; s.w += p.w;
        }
        *(float4*)(KVf + (size_t)nh * 4096 + (size_t)e * 4) = s;
    }
    if (t < 64) {
        float s = 0.0f;
        for (int c2 = 0; c2 < NC; ++c2) s += pKs[((size_t)c2 * 32 + nh) * 64 + t];
        Ksf[nh * 64 + t] = s;
    }
}

// ---------------- Phase 2: out[l,v] = (Qf . KV[:,v]) / (Qf . Ksum + eps) ----------------
__global__ __launch_bounds__(256) void k_phase2(const float* __restrict__ Qin,
                                                const float* __restrict__ KVf,
                                                const float* __restrict__ Ksf,
                                                float* __restrict__ Out) {
    const int nh   = blockIdx.x & 31;
    const int tile = blockIdx.x >> 5;   // 64 tiles of 64 rows
    const int n = nh >> 3, h = nh & 7;
    const int t = threadIdx.x;
    const int wv = t >> 6, lane = t & 63;

    // lane holds KV column `lane`: kvreg[d] = KV[d][lane]
    float kvreg[64];
    const float* kvbase = KVf + (size_t)nh * 4096 + lane;
#pragma unroll
    for (int d = 0; d < 64; ++d) kvreg[d] = kvbase[d * 64];
    const float ksreg = Ksf[nh * 64 + lane];

    const int l0 = tile * 64 + wv * 16;
    for (int rr = 0; rr < 16; ++rr) {
        const int l = l0 + rr;
        const size_t g = ((size_t)(n * SEQ + l) * NH + h) * DIM + lane;
        const float q = Qin[g];
        const float qf = elu1(q);
        // normalizer: z = 1/(sum_d qf_d * Ksum_d + eps), butterfly across the wave
        float p = qf * ksreg;
#pragma unroll
        for (int off = 32; off >= 1; off >>= 1) p += __shfl_xor(p, off, 64);
        const float z = 1.0f / (p + 1e-6f);
        float acc = 0.0f;
#pragma unroll
        for (int d = 0; d < 64; ++d) {
            const float qd = __shfl(qf, d, 64);   // broadcast Qf[l][d] (v_readlane)
            acc = fmaf(qd, kvreg[d], acc);
        }
        Out[g] = acc * z;
    }
}

extern "C" void kernel_launch(void* const* d_in, const int* in_sizes, int n_in,
                              void* d_out, int out_size, void* d_ws, size_t ws_size,
                              hipStream_t stream) {
    const float* Q = (const float*)d_in[0];
    const float* K = (const float*)d_in[1];
    const float* V = (const float*)d_in[2];
    float* out = (float*)d_out;

    // ws layout: [KVf 32*4096][Ksf 32*64][pKV NC*32*4096][pKs NC*32*64]
    int NC = 32;
    const size_t unit = 133120ull * 4ull; // (4096+64)*32 floats in bytes
    while (NC > 1 && (size_t)(NC + 1) * unit > ws_size) NC >>= 1;
    const int sLen = SEQ / NC;

    float* KVf = (float*)d_ws;
    float* Ksf = KVf + 32 * 4096;
    float* pKV = Ksf + 32 * 64;
    float* pKs = pKV + (size_t)NC * 32 * 4096;

    hipLaunchKernelGGL(k_phase1, dim3(32 * NC), dim3(256), 0, stream, K, V, pKV, pKs, NC, sLen);
    hipLaunchKernelGGL(k_reduce, dim3(32), dim3(256), 0, stream, pKV, pKs, KVf, Ksf, NC);
    hipLaunchKernelGGL(k_phase2, dim3(2048), dim3(256), 0, stream, Q, KVf, Ksf, out);
}

// Round 2
// 91.401 us; speedup vs baseline: 1.8420x; 1.8420x over previous
//
#include <hip/hip_runtime.h>
#include <math.h>

#define SEQ 4096
#define NH  8
#define DIM 64
// 32 (n,h) pairs total: n=4, h=8

__device__ __forceinline__ float elu1(float x) {
    // jax.nn.elu(x)+1 = x+1 (x>0) else exp(x)
    return x > 0.0f ? x + 1.0f : __expf(x);
}

// ---------------- Phase 1: partial KV (64x64) + partial Ksum per (n,h,chunk) ----------------
// Double-buffered LDS, one barrier per 16-row tile, global loads issued before compute.
__global__ __launch_bounds__(256) void k_phase1(const float* __restrict__ Kin,
                                                const float* __restrict__ Vin,
                                                float* __restrict__ pKV,
                                                float* __restrict__ pKs,
                                                int NC, int sLen) {
    const int nh = blockIdx.x / NC;
    const int ck = blockIdx.x % NC;
    const int n  = nh >> 3, h = nh & 7;
    const int t  = threadIdx.x;
    const int r  = t >> 4;          // staging row 0..15
    const int c  = (t & 15) * 4;    // staging col (x4)
    const int d0 = (t >> 4) * 4;    // owned d block
    const int v0 = (t & 15) * 4;    // owned v block

    __shared__ __align__(16) float kf[2][16][64];
    __shared__ __align__(16) float vv[2][16][64];

    float acc[4][4];
#pragma unroll
    for (int i = 0; i < 4; i++)
#pragma unroll
        for (int j = 0; j < 4; j++) acc[i][j] = 0.0f;
    float ks[4] = {0.0f, 0.0f, 0.0f, 0.0f};

    const int s0 = ck * sLen;
    const int iters = sLen >> 4;

    // prologue: stage tile 0 into buffer 0
    {
        const size_t g = ((size_t)(n * SEQ + s0 + r) * NH + h) * DIM + c;
        float4 k4 = *(const float4*)(Kin + g);
        float4 v4 = *(const float4*)(Vin + g);
        float4 f4;
        f4.x = elu1(k4.x); f4.y = elu1(k4.y); f4.z = elu1(k4.z); f4.w = elu1(k4.w);
        ks[0] += f4.x; ks[1] += f4.y; ks[2] += f4.z; ks[3] += f4.w;
        *(float4*)&kf[0][r][c] = f4;
        *(float4*)&vv[0][r][c] = v4;
    }

    for (int it = 0; it < iters; ++it) {
        __syncthreads();                 // tile `it` visible; prior-iter reads done
        const int cur = it & 1;
        float4 k4, v4;
        const bool more = (it + 1 < iters);
        if (more) {                      // issue next tile's loads early (latency hidden under fma)
            const size_t g = ((size_t)(n * SEQ + s0 + (it + 1) * 16 + r) * NH + h) * DIM + c;
            k4 = *(const float4*)(Kin + g);
            v4 = *(const float4*)(Vin + g);
        }
#pragma unroll
        for (int ss = 0; ss < 16; ++ss) {
            float4 a4 = *(const float4*)&kf[cur][ss][d0];
            float4 b4 = *(const float4*)&vv[cur][ss][v0];
            float a[4] = {a4.x, a4.y, a4.z, a4.w};
            float b[4] = {b4.x, b4.y, b4.z, b4.w};
#pragma unroll
            for (int i = 0; i < 4; i++)
#pragma unroll
                for (int j = 0; j < 4; j++)
                    acc[i][j] = fmaf(a[i], b[j], acc[i][j]);
        }
        if (more) {                      // write next tile into the other buffer (not read this iter)
            float4 f4;
            f4.x = elu1(k4.x); f4.y = elu1(k4.y); f4.z = elu1(k4.z); f4.w = elu1(k4.w);
            ks[0] += f4.x; ks[1] += f4.y; ks[2] += f4.z; ks[3] += f4.w;
            *(float4*)&kf[cur ^ 1][r][c] = f4;
            *(float4*)&vv[cur ^ 1][r][c] = v4;
        }
    }

    // store partial KV: layout pKV[(ck*32+nh)][d][v]
    float* dst = pKV + ((size_t)ck * 32 + nh) * 4096;
#pragma unroll
    for (int i = 0; i < 4; i++) {
        float4 o;
        o.x = acc[i][0]; o.y = acc[i][1]; o.z = acc[i][2]; o.w = acc[i][3];
        *(float4*)(dst + (d0 + i) * 64 + v0) = o;
    }

    // Ksum reduce via LDS (reuse kf[0]; guarded by barrier)
    __syncthreads();
    *(float4*)&kf[0][r][c] = make_float4(ks[0], ks[1], ks[2], ks[3]);
    __syncthreads();
    if (t < 64) {
        float s = 0.0f;
#pragma unroll
        for (int rr = 0; rr < 16; ++rr) s += kf[0][rr][t];
        pKs[((size_t)ck * 32 + nh) * 64 + t] = s;
    }
}

// ---------------- Reduce partials -> final KV, Ksum ----------------
__global__ __launch_bounds__(256) void k_reduce(const float* __restrict__ pKV,
                                                const float* __restrict__ pKs,
                                                float* __restrict__ KVf,
                                                float* __restrict__ Ksf,
                                                int NC) {
    const int nh = blockIdx.x;
    const int t = threadIdx.x;
    for (int e = t; e < 1024; e += 256) {   // 1024 float4 = 4096 floats
        float4 s = make_float4(0.f, 0.f, 0.f, 0.f);
        for (int c2 = 0; c2 < NC; ++c2) {
            float4 p = *(const float4*)(pKV + ((size_t)c2 * 32 + nh) * 4096 + (size_t)e * 4);
            s.x += p.x; s.y += p.y; s.z += p.z; s.w += p.w;
        }
        *(float4*)(KVf + (size_t)nh * 4096 + (size_t)e * 4) = s;
    }
    if (t < 64) {
        float s = 0.0f;
        for (int c2 = 0; c2 < NC; ++c2) s += pKs[((size_t)c2 * 32 + nh) * 64 + t];
        Ksf[nh * 64 + t] = s;
    }
}

// ---------------- Phase 2: register-tiled GEMM, out[l,v] = (Qf.KV[:,v]) / (Qf.Ks + eps) ----------------
// Block: 256 threads, 128 Q-rows. Per-thread: 4 rows x 8 cols + normalizer.
#define P2_ROWS 128
__global__ __launch_bounds__(256) void k_phase2(const float* __restrict__ Qin,
                                                const float* __restrict__ KVf,
                                                const float* __restrict__ Ksf,
                                                float* __restrict__ Out) {
    const int nh   = blockIdx.x >> 5;   // consecutive blocks share KV in L2
    const int tile = blockIdx.x & 31;   // 32 tiles of 128 rows
    const int n = nh >> 3, h = nh & 7;
    const int t = threadIdx.x;

    __shared__ __align__(16) float Qt[64][132];  // transposed qf, +4 pad: conflict-free b128 reads
    __shared__ __align__(16) float KVs[64][64];
    __shared__ float Kss[64];

    // stage KV (row-major, coalesced)
    {
        const float4* src = (const float4*)(KVf + (size_t)nh * 4096);
        float4* dst = (float4*)&KVs[0][0];
#pragma unroll
        for (int i = 0; i < 4; ++i) {
            int idx = t + 256 * i;   // 1024 float4
            dst[idx] = src[idx];
        }
        if (t < 64) Kss[t] = Ksf[nh * 64 + t];
    }

    // stage Q tile transposed, elu applied
    const int l0 = tile * P2_ROWS;
    {
#pragma unroll
        for (int i = 0; i < 8; ++i) {
            int j = t + 256 * i;          // 2048 float4 = 128 rows x 16
            int row = j >> 4;             // 0..127
            int c4  = (j & 15) * 4;       // 0..60
            const size_t g = ((size_t)(n * SEQ + l0 + row) * NH + h) * DIM + c4;
            float4 q4 = *(const float4*)(Qin + g);
            Qt[c4 + 0][row] = elu1(q4.x);
            Qt[c4 + 1][row] = elu1(q4.y);
            Qt[c4 + 2][row] = elu1(q4.z);
            Qt[c4 + 3][row] = elu1(q4.w);
        }
    }
    __syncthreads();

    const int v0 = (t & 7) * 8;      // owned col block (8 cols)
    const int r0 = (t >> 3) * 4;     // owned row block (4 rows), 0..124

    float acc[4][8];
#pragma unroll
    for (int i = 0; i < 4; i++)
#pragma unroll
        for (int j = 0; j < 8; j++) acc[i][j] = 0.0f;
    float p[4] = {0.f, 0.f, 0.f, 0.f};

#pragma unroll 16
    for (int d = 0; d < 64; ++d) {
        float4 qt = *(const float4*)&Qt[d][r0];
        float4 ka = *(const float4*)&KVs[d][v0];
        float4 kb = *(const float4*)&KVs[d][v0 + 4];
        float ksd = Kss[d];
        float q[4]  = {qt.x, qt.y, qt.z, qt.w};
        float kv[8] = {ka.x, ka.y, ka.z, ka.w, kb.x, kb.y, kb.z, kb.w};
#pragma unroll
        for (int i = 0; i < 4; i++) {
            p[i] = fmaf(q[i], ksd, p[i]);
#pragma unroll
            for (int j = 0; j < 8; j++)
                acc[i][j] = fmaf(q[i], kv[j], acc[i][j]);
        }
    }

    // epilogue: scale by 1/(p+eps), coalesced float4 stores
#pragma unroll
    for (int i = 0; i < 4; i++) {
        const float z = 1.0f / (p[i] + 1e-6f);
        const int l = l0 + r0 + i;
        float* o = Out + ((size_t)(n * SEQ + l) * NH + h) * DIM + v0;
        float4 oa, ob;
        oa.x = acc[i][0] * z; oa.y = acc[i][1] * z; oa.z = acc[i][2] * z; oa.w = acc[i][3] * z;
        ob.x = acc[i][4] * z; ob.y = acc[i][5] * z; ob.z = acc[i][6] * z; ob.w = acc[i][7] * z;
        *(float4*)(o)     = oa;
        *(float4*)(o + 4) = ob;
    }
}

extern "C" void kernel_launch(void* const* d_in, const int* in_sizes, int n_in,
                              void* d_out, int out_size, void* d_ws, size_t ws_size,
                              hipStream_t stream) {
    const float* Q = (const float*)d_in[0];
    const float* K = (const float*)d_in[1];
    const float* V = (const float*)d_in[2];
    float* out = (float*)d_out;

    // ws layout: [KVf 32*4096][Ksf 32*64][pKV NC*32*4096][pKs NC*32*64]
    int NC = 32;
    const size_t unit = 133120ull * 4ull; // (4096+64)*32 floats in bytes
    while (NC > 1 && (size_t)(NC + 1) * unit > ws_size) NC >>= 1;
    const int sLen = SEQ / NC;

    float* KVf = (float*)d_ws;
    float* Ksf = KVf + 32 * 4096;
    float* pKV = Ksf + 32 * 64;
    float* pKs = pKV + (size_t)NC * 32 * 4096;

    hipLaunchKernelGGL(k_phase1, dim3(32 * NC), dim3(256), 0, stream, K, V, pKV, pKs, NC, sLen);
    hipLaunchKernelGGL(k_reduce, dim3(32), dim3(256), 0, stream, pKV, pKs, KVf, Ksf, NC);
    hipLaunchKernelGGL(k_phase2, dim3(1024), dim3(256), 0, stream, Q, KVf, Ksf, out);
}

// Round 3
// 68.509 us; speedup vs baseline: 2.4574x; 1.3341x over previous
//
#include <hip/hip_runtime.h>
#include <math.h>

#define SEQ 4096
#define NH  8
#define DIM 64
// 32 (n,h) pairs total: n=4, h=8

__device__ __forceinline__ float elu1(float x) {
    // jax.nn.elu(x)+1 = x+1 (x>0) else exp(x)
    return x > 0.0f ? x + 1.0f : __expf(x);
}

// ---------------- Phase 1: partial KV (64x64) + partial Ksum per (n,h,chunk) ----------------
// Double-buffered LDS, one barrier per 16-row tile, global loads issued before compute.
__global__ __launch_bounds__(256) void k_phase1(const float* __restrict__ Kin,
                                                const float* __restrict__ Vin,
                                                float* __restrict__ pKV,
                                                float* __restrict__ pKs,
                                                int NC, int sLen) {
    const int nh = blockIdx.x / NC;
    const int ck = blockIdx.x % NC;
    const int n  = nh >> 3, h = nh & 7;
    const int t  = threadIdx.x;
    const int r  = t >> 4;          // staging row 0..15
    const int c  = (t & 15) * 4;    // staging col (x4)
    const int d0 = (t >> 4) * 4;    // owned d block
    const int v0 = (t & 15) * 4;    // owned v block

    __shared__ __align__(16) float kf[2][16][64];
    __shared__ __align__(16) float vv[2][16][64];

    float acc[4][4];
#pragma unroll
    for (int i = 0; i < 4; i++)
#pragma unroll
        for (int j = 0; j < 4; j++) acc[i][j] = 0.0f;
    float ks[4] = {0.0f, 0.0f, 0.0f, 0.0f};

    const int s0 = ck * sLen;
    const int iters = sLen >> 4;

    // prologue: stage tile 0 into buffer 0
    {
        const size_t g = ((size_t)(n * SEQ + s0 + r) * NH + h) * DIM + c;
        float4 k4 = *(const float4*)(Kin + g);
        float4 v4 = *(const float4*)(Vin + g);
        float4 f4;
        f4.x = elu1(k4.x); f4.y = elu1(k4.y); f4.z = elu1(k4.z); f4.w = elu1(k4.w);
        ks[0] += f4.x; ks[1] += f4.y; ks[2] += f4.z; ks[3] += f4.w;
        *(float4*)&kf[0][r][c] = f4;
        *(float4*)&vv[0][r][c] = v4;
    }

    for (int it = 0; it < iters; ++it) {
        __syncthreads();                 // tile `it` visible; prior-iter reads done
        const int cur = it & 1;
        float4 k4, v4;
        const bool more = (it + 1 < iters);
        if (more) {                      // issue next tile's loads early (latency hidden under fma)
            const size_t g = ((size_t)(n * SEQ + s0 + (it + 1) * 16 + r) * NH + h) * DIM + c;
            k4 = *(const float4*)(Kin + g);
            v4 = *(const float4*)(Vin + g);
        }
#pragma unroll
        for (int ss = 0; ss < 16; ++ss) {
            float4 a4 = *(const float4*)&kf[cur][ss][d0];
            float4 b4 = *(const float4*)&vv[cur][ss][v0];
            float a[4] = {a4.x, a4.y, a4.z, a4.w};
            float b[4] = {b4.x, b4.y, b4.z, b4.w};
#pragma unroll
            for (int i = 0; i < 4; i++)
#pragma unroll
                for (int j = 0; j < 4; j++)
                    acc[i][j] = fmaf(a[i], b[j], acc[i][j]);
        }
        if (more) {                      // write next tile into the other buffer (not read this iter)
            float4 f4;
            f4.x = elu1(k4.x); f4.y = elu1(k4.y); f4.z = elu1(k4.z); f4.w = elu1(k4.w);
            ks[0] += f4.x; ks[1] += f4.y; ks[2] += f4.z; ks[3] += f4.w;
            *(float4*)&kf[cur ^ 1][r][c] = f4;
            *(float4*)&vv[cur ^ 1][r][c] = v4;
        }
    }

    // store partial KV: layout pKV[(ck*32+nh)][d][v]
    float* dst = pKV + ((size_t)ck * 32 + nh) * 4096;
#pragma unroll
    for (int i = 0; i < 4; i++) {
        float4 o;
        o.x = acc[i][0]; o.y = acc[i][1]; o.z = acc[i][2]; o.w = acc[i][3];
        *(float4*)(dst + (d0 + i) * 64 + v0) = o;
    }

    // Ksum reduce via LDS (reuse kf[0]; guarded by barrier)
    __syncthreads();
    *(float4*)&kf[0][r][c] = make_float4(ks[0], ks[1], ks[2], ks[3]);
    __syncthreads();
    if (t < 64) {
        float s = 0.0f;
#pragma unroll
        for (int rr = 0; rr < 16; ++rr) s += kf[0][rr][t];
        pKs[((size_t)ck * 32 + nh) * 64 + t] = s;
    }
}

// ---------------- Reduce partials -> final KV, Ksum (parallel: 128 blocks) ----------------
__global__ __launch_bounds__(256) void k_reduce(const float* __restrict__ pKV,
                                                const float* __restrict__ pKs,
                                                float* __restrict__ KVf,
                                                float* __restrict__ Ksf,
                                                int NC) {
    const int gid = blockIdx.x * 256 + threadIdx.x;   // 0..32767, one float4 each
    const float4* p4 = (const float4*)pKV;
    float4 s = make_float4(0.f, 0.f, 0.f, 0.f);
    for (int c = 0; c < NC; ++c) {
        float4 v = p4[(size_t)c * 32768 + gid];
        s.x += v.x; s.y += v.y; s.z += v.z; s.w += v.w;
    }
    ((float4*)KVf)[gid] = s;
    if (gid < 2048) {
        float ss = 0.0f;
        for (int c = 0; c < NC; ++c) ss += pKs[(size_t)c * 2048 + gid];
        Ksf[gid] = ss;
    }
}

// ---------------- Phase 2: register-tiled GEMM, out[l,v] = (Qf.KV[:,v]) / (Qf.Ks + eps) ----------------
// 512 blocks (32 nh x 16 tiles of 256 rows), 256 threads, 8x8 per-thread tile.
// Qt is d-chunked [32][256], un-padded, XOR-swizzled: col' = row ^ (d & ~3).
//   -> transpose writes and b128 reads are both <=2-way bank aliased (free).
__global__ __launch_bounds__(256, 3) void k_phase2(const float* __restrict__ Qin,
                                                   const float* __restrict__ KVf,
                                                   const float* __restrict__ Ksf,
                                                   float* __restrict__ Out) {
    const int nh   = blockIdx.x >> 4;
    const int tile = blockIdx.x & 15;
    const int n = nh >> 3, h = nh & 7;
    const int t = threadIdx.x;

    __shared__ __align__(16) float Qt[32 * 256];   // 32 KB, swizzled transpose chunk
    __shared__ __align__(16) float KVs[64][64];    // 16 KB
    __shared__ float Kss[64];

    // stage KV + Ksum (coalesced; small, L2-resident)
    {
        const float4* src = (const float4*)(KVf + (size_t)nh * 4096);
        float4* dst = (float4*)&KVs[0][0];
#pragma unroll
        for (int i = 0; i < 4; ++i) dst[t + 256 * i] = src[t + 256 * i];
        if (t < 64) Kss[t] = Ksf[nh * 64 + t];
    }

    const int l0 = tile * 256;
    const int r0 = (t >> 3) * 8;     // owned rows (8)
    const int v0 = (t & 7) * 8;      // owned cols (8)

    float acc[8][8];
#pragma unroll
    for (int i = 0; i < 8; i++)
#pragma unroll
        for (int j = 0; j < 8; j++) acc[i][j] = 0.0f;
    float p[8] = {0.f, 0.f, 0.f, 0.f, 0.f, 0.f, 0.f, 0.f};

    for (int dc = 0; dc < 2; ++dc) {
        if (dc) __syncthreads();       // protect Qt before overwrite
        // stage Q chunk transposed+swizzled: 2048 float4, coalesced global reads
#pragma unroll
        for (int i = 0; i < 8; ++i) {
            const int j   = t + 256 * i;
            const int row = j >> 3;           // 0..255
            const int dl4 = (j & 7) << 2;     // local d (float4 start), 0..28
            const size_t g = ((size_t)(n * SEQ + l0 + row) * NH + h) * DIM + dc * 32 + dl4;
            float4 q4 = *(const float4*)(Qin + g);
            const int col = row ^ dl4;        // swizzle s(d) = d & ~3 = dl4 for d in [dl4, dl4+4)
            Qt[(dl4 + 0) * 256 + col] = elu1(q4.x);
            Qt[(dl4 + 1) * 256 + col] = elu1(q4.y);
            Qt[(dl4 + 2) * 256 + col] = elu1(q4.z);
            Qt[(dl4 + 3) * 256 + col] = elu1(q4.w);
        }
        __syncthreads();

#pragma unroll 8
        for (int dl = 0; dl < 32; ++dl) {
            const int d = dc * 32 + dl;
            const int s = dl & ~3;
            float4 qa = *(const float4*)&Qt[dl * 256 + (r0 ^ s)];
            float4 qb = *(const float4*)&Qt[dl * 256 + ((r0 + 4) ^ s)];
            float4 ka = *(const float4*)&KVs[d][v0];
            float4 kb = *(const float4*)&KVs[d][v0 + 4];
            const float ksd = Kss[d];
            float q[8]  = {qa.x, qa.y, qa.z, qa.w, qb.x, qb.y, qb.z, qb.w};
            float kv[8] = {ka.x, ka.y, ka.z, ka.w, kb.x, kb.y, kb.z, kb.w};
#pragma unroll
            for (int i = 0; i < 8; ++i) {
                p[i] = fmaf(q[i], ksd, p[i]);
#pragma unroll
                for (int jj = 0; jj < 8; ++jj)
                    acc[i][jj] = fmaf(q[i], kv[jj], acc[i][jj]);
            }
        }
    }

    // epilogue: scale by 1/(p+eps), float4 stores
#pragma unroll
    for (int i = 0; i < 8; ++i) {
        const float z = 1.0f / (p[i] + 1e-6f);
        const int l = l0 + r0 + i;
        float* o = Out + ((size_t)(n * SEQ + l) * NH + h) * DIM + v0;
        float4 oa, ob;
        oa.x = acc[i][0] * z; oa.y = acc[i][1] * z; oa.z = acc[i][2] * z; oa.w = acc[i][3] * z;
        ob.x = acc[i][4] * z; ob.y = acc[i][5] * z; ob.z = acc[i][6] * z; ob.w = acc[i][7] * z;
        *(float4*)(o)     = oa;
        *(float4*)(o + 4) = ob;
    }
}

extern "C" void kernel_launch(void* const* d_in, const int* in_sizes, int n_in,
                              void* d_out, int out_size, void* d_ws, size_t ws_size,
                              hipStream_t stream) {
    const float* Q = (const float*)d_in[0];
    const float* K = (const float*)d_in[1];
    const float* V = (const float*)d_in[2];
    float* out = (float*)d_out;

    // ws layout: [KVf 32*4096][Ksf 32*64][pKV NC*32*4096][pKs NC*32*64]
    int NC = 32;
    const size_t unit = 133120ull * 4ull; // (4096+64)*32 floats in bytes
    while (NC > 1 && (size_t)(NC + 1) * unit > ws_size) NC >>= 1;
    const int sLen = SEQ / NC;

    float* KVf = (float*)d_ws;
    float* Ksf = KVf + 32 * 4096;
    float* pKV = Ksf + 32 * 64;
    float* pKs = pKV + (size_t)NC * 32 * 4096;

    hipLaunchKernelGGL(k_phase1, dim3(32 * NC), dim3(256), 0, stream, K, V, pKV, pKs, NC, sLen);
    hipLaunchKernelGGL(k_reduce, dim3(128), dim3(256), 0, stream, pKV, pKs, KVf, Ksf, NC);
    hipLaunchKernelGGL(k_phase2, dim3(512), dim3(256), 0, stream, Q, KVf, Ksf, out);
}

// Round 4
// 56.783 us; speedup vs baseline: 2.9649x; 1.2065x over previous
//
#include <hip/hip_runtime.h>
#include <math.h>

#define SEQ 4096
#define NH  8
#define DIM 64
// 32 (n,h) pairs total: n=4, h=8

__device__ __forceinline__ float elu1(float x) {
    // jax.nn.elu(x)+1 = x+1 (x>0) else exp(x)
    return x > 0.0f ? x + 1.0f : __expf(x);
}

// ---------------- Phase 1: partial KV (64x64) + partial Ksum per (n,h,chunk) ----------------
// Double-buffered LDS, one barrier per 16-row tile, global loads issued before compute.
__global__ __launch_bounds__(256) void k_phase1(const float* __restrict__ Kin,
                                                const float* __restrict__ Vin,
                                                float* __restrict__ pKV,
                                                float* __restrict__ pKs,
                                                int NC, int sLen) {
    const int nh = blockIdx.x / NC;
    const int ck = blockIdx.x % NC;
    const int n  = nh >> 3, h = nh & 7;
    const int t  = threadIdx.x;
    const int r  = t >> 4;          // staging row 0..15
    const int c  = (t & 15) * 4;    // staging col (x4)
    const int d0 = (t >> 4) * 4;    // owned d block
    const int v0 = (t & 15) * 4;    // owned v block

    __shared__ __align__(16) float kf[2][16][64];
    __shared__ __align__(16) float vv[2][16][64];

    float acc[4][4];
#pragma unroll
    for (int i = 0; i < 4; i++)
#pragma unroll
        for (int j = 0; j < 4; j++) acc[i][j] = 0.0f;
    float ks[4] = {0.0f, 0.0f, 0.0f, 0.0f};

    const int s0 = ck * sLen;
    const int iters = sLen >> 4;

    // prologue: stage tile 0 into buffer 0
    {
        const size_t g = ((size_t)(n * SEQ + s0 + r) * NH + h) * DIM + c;
        float4 k4 = *(const float4*)(Kin + g);
        float4 v4 = *(const float4*)(Vin + g);
        float4 f4;
        f4.x = elu1(k4.x); f4.y = elu1(k4.y); f4.z = elu1(k4.z); f4.w = elu1(k4.w);
        ks[0] += f4.x; ks[1] += f4.y; ks[2] += f4.z; ks[3] += f4.w;
        *(float4*)&kf[0][r][c] = f4;
        *(float4*)&vv[0][r][c] = v4;
    }

    for (int it = 0; it < iters; ++it) {
        __syncthreads();                 // tile `it` visible; prior-iter reads done
        const int cur = it & 1;
        float4 k4, v4;
        const bool more = (it + 1 < iters);
        if (more) {                      // issue next tile's loads early (latency hidden under fma)
            const size_t g = ((size_t)(n * SEQ + s0 + (it + 1) * 16 + r) * NH + h) * DIM + c;
            k4 = *(const float4*)(Kin + g);
            v4 = *(const float4*)(Vin + g);
        }
#pragma unroll
        for (int ss = 0; ss < 16; ++ss) {
            float4 a4 = *(const float4*)&kf[cur][ss][d0];
            float4 b4 = *(const float4*)&vv[cur][ss][v0];
            float a[4] = {a4.x, a4.y, a4.z, a4.w};
            float b[4] = {b4.x, b4.y, b4.z, b4.w};
#pragma unroll
            for (int i = 0; i < 4; i++)
#pragma unroll
                for (int j = 0; j < 4; j++)
                    acc[i][j] = fmaf(a[i], b[j], acc[i][j]);
        }
        if (more) {                      // write next tile into the other buffer (not read this iter)
            float4 f4;
            f4.x = elu1(k4.x); f4.y = elu1(k4.y); f4.z = elu1(k4.z); f4.w = elu1(k4.w);
            ks[0] += f4.x; ks[1] += f4.y; ks[2] += f4.z; ks[3] += f4.w;
            *(float4*)&kf[cur ^ 1][r][c] = f4;
            *(float4*)&vv[cur ^ 1][r][c] = v4;
        }
    }

    // store partial KV: layout pKV[(ck*32+nh)][d][v]
    float* dst = pKV + ((size_t)ck * 32 + nh) * 4096;
#pragma unroll
    for (int i = 0; i < 4; i++) {
        float4 o;
        o.x = acc[i][0]; o.y = acc[i][1]; o.z = acc[i][2]; o.w = acc[i][3];
        *(float4*)(dst + (d0 + i) * 64 + v0) = o;
    }

    // Ksum reduce via LDS (reuse kf[0]; guarded by barrier)
    __syncthreads();
    *(float4*)&kf[0][r][c] = make_float4(ks[0], ks[1], ks[2], ks[3]);
    __syncthreads();
    if (t < 64) {
        float s = 0.0f;
#pragma unroll
        for (int rr = 0; rr < 16; ++rr) s += kf[0][rr][t];
        pKs[((size_t)ck * 32 + nh) * 64 + t] = s;
    }
}

// ---------------- Reduce partials -> final KV, Ksum ----------------
// 256 blocks x 128 threads: every CU busy; NC templated so the chunk loop
// fully unrolls and loads pipeline (no dependent-load latency chain).
template <int NC>
__global__ __launch_bounds__(128) void k_reduceT(const float* __restrict__ pKV,
                                                 const float* __restrict__ pKs,
                                                 float* __restrict__ KVf,
                                                 float* __restrict__ Ksf) {
    const int gid = blockIdx.x * 128 + threadIdx.x;   // 0..32767, one float4 each
    const float4* p4 = (const float4*)pKV;
    float4 s = make_float4(0.f, 0.f, 0.f, 0.f);
#pragma unroll
    for (int c = 0; c < NC; ++c) {
        float4 v = p4[(size_t)c * 32768 + gid];
        s.x += v.x; s.y += v.y; s.z += v.z; s.w += v.w;
    }
    ((float4*)KVf)[gid] = s;
    if (gid < 2048) {
        float ss = 0.0f;
#pragma unroll
        for (int c = 0; c < NC; ++c) ss += pKs[(size_t)c * 2048 + gid];
        Ksf[gid] = ss;
    }
}

__global__ __launch_bounds__(128) void k_reduceG(const float* __restrict__ pKV,
                                                 const float* __restrict__ pKs,
                                                 float* __restrict__ KVf,
                                                 float* __restrict__ Ksf, int NC) {
    const int gid = blockIdx.x * 128 + threadIdx.x;
    const float4* p4 = (const float4*)pKV;
    float4 s = make_float4(0.f, 0.f, 0.f, 0.f);
    for (int c = 0; c < NC; ++c) {
        float4 v = p4[(size_t)c * 32768 + gid];
        s.x += v.x; s.y += v.y; s.z += v.z; s.w += v.w;
    }
    ((float4*)KVf)[gid] = s;
    if (gid < 2048) {
        float ss = 0.0f;
        for (int c = 0; c < NC; ++c) ss += pKs[(size_t)c * 2048 + gid];
        Ksf[gid] = ss;
    }
}

// ---------------- Phase 2: register-tiled GEMM, out[l,v] = (Qf.KV[:,v]) / (Qf.Ks + eps) ----------------
// 512 blocks (32 nh x 16 tiles of 256 rows), 256 threads, 8x8 per-thread tile.
// Qt is d-chunked [32][256], un-padded, XOR-swizzled: col' = row ^ (d & ~3).
//   -> transpose writes and b128 reads are both <=2-way bank aliased (free).
// NOTE: no min-waves cap and only unroll-2 on the d-loop — round 3's
// launch_bounds(256,3)+unroll-8 forced ~200 live VGPRs under a 168 cap -> spills.
__global__ __launch_bounds__(256) void k_phase2(const float* __restrict__ Qin,
                                                const float* __restrict__ KVf,
                                                const float* __restrict__ Ksf,
                                                float* __restrict__ Out) {
    const int nh   = blockIdx.x >> 4;
    const int tile = blockIdx.x & 15;
    const int n = nh >> 3, h = nh & 7;
    const int t = threadIdx.x;

    __shared__ __align__(16) float Qt[32 * 256];   // 32 KB, swizzled transpose chunk
    __shared__ __align__(16) float KVs[64][64];    // 16 KB
    __shared__ float Kss[64];

    // stage KV + Ksum (coalesced; small, L2-resident)
    {
        const float4* src = (const float4*)(KVf + (size_t)nh * 4096);
        float4* dst = (float4*)&KVs[0][0];
#pragma unroll
        for (int i = 0; i < 4; ++i) dst[t + 256 * i] = src[t + 256 * i];
        if (t < 64) Kss[t] = Ksf[nh * 64 + t];
    }

    const int l0 = tile * 256;
    const int r0 = (t >> 3) * 8;     // owned rows (8)
    const int v0 = (t & 7) * 8;      // owned cols (8)

    float acc[8][8];
#pragma unroll
    for (int i = 0; i < 8; i++)
#pragma unroll
        for (int j = 0; j < 8; j++) acc[i][j] = 0.0f;
    float p[8] = {0.f, 0.f, 0.f, 0.f, 0.f, 0.f, 0.f, 0.f};

    for (int dc = 0; dc < 2; ++dc) {
        if (dc) __syncthreads();       // protect Qt before overwrite
        // stage Q chunk transposed+swizzled: 2048 float4, coalesced global reads
#pragma unroll
        for (int i = 0; i < 8; ++i) {
            const int j   = t + 256 * i;
            const int row = j >> 3;           // 0..255
            const int dl4 = (j & 7) << 2;     // local d (float4 start), 0..28
            const size_t g = ((size_t)(n * SEQ + l0 + row) * NH + h) * DIM + dc * 32 + dl4;
            float4 q4 = *(const float4*)(Qin + g);
            const int col = row ^ dl4;        // swizzle s(d) = d & ~3 = dl4 for d in [dl4, dl4+4)
            Qt[(dl4 + 0) * 256 + col] = elu1(q4.x);
            Qt[(dl4 + 1) * 256 + col] = elu1(q4.y);
            Qt[(dl4 + 2) * 256 + col] = elu1(q4.z);
            Qt[(dl4 + 3) * 256 + col] = elu1(q4.w);
        }
        __syncthreads();

#pragma unroll 2
        for (int dl = 0; dl < 32; ++dl) {
            const int d = dc * 32 + dl;
            const int s = dl & ~3;
            float4 qa = *(const float4*)&Qt[dl * 256 + (r0 ^ s)];
            float4 qb = *(const float4*)&Qt[dl * 256 + ((r0 + 4) ^ s)];
            float4 ka = *(const float4*)&KVs[d][v0];
            float4 kb = *(const float4*)&KVs[d][v0 + 4];
            const float ksd = Kss[d];
            float q[8]  = {qa.x, qa.y, qa.z, qa.w, qb.x, qb.y, qb.z, qb.w};
            float kv[8] = {ka.x, ka.y, ka.z, ka.w, kb.x, kb.y, kb.z, kb.w};
#pragma unroll
            for (int i = 0; i < 8; ++i) {
                p[i] = fmaf(q[i], ksd, p[i]);
#pragma unroll
                for (int jj = 0; jj < 8; ++jj)
                    acc[i][jj] = fmaf(q[i], kv[jj], acc[i][jj]);
            }
        }
    }

    // epilogue: scale by 1/(p+eps), float4 stores
#pragma unroll
    for (int i = 0; i < 8; ++i) {
        const float z = 1.0f / (p[i] + 1e-6f);
        const int l = l0 + r0 + i;
        float* o = Out + ((size_t)(n * SEQ + l) * NH + h) * DIM + v0;
        float4 oa, ob;
        oa.x = acc[i][0] * z; oa.y = acc[i][1] * z; oa.z = acc[i][2] * z; oa.w = acc[i][3] * z;
        ob.x = acc[i][4] * z; ob.y = acc[i][5] * z; ob.z = acc[i][6] * z; ob.w = acc[i][7] * z;
        *(float4*)(o)     = oa;
        *(float4*)(o + 4) = ob;
    }
}

extern "C" void kernel_launch(void* const* d_in, const int* in_sizes, int n_in,
                              void* d_out, int out_size, void* d_ws, size_t ws_size,
                              hipStream_t stream) {
    const float* Q = (const float*)d_in[0];
    const float* K = (const float*)d_in[1];
    const float* V = (const float*)d_in[2];
    float* out = (float*)d_out;

    // ws layout: [KVf 32*4096][Ksf 32*64][pKV NC*32*4096][pKs NC*32*64]
    int NC = 32;
    const size_t unit = 133120ull * 4ull; // (4096+64)*32 floats in bytes
    while (NC > 1 && (size_t)(NC + 1) * unit > ws_size) NC >>= 1;
    const int sLen = SEQ / NC;

    float* KVf = (float*)d_ws;
    float* Ksf = KVf + 32 * 4096;
    float* pKV = Ksf + 32 * 64;
    float* pKs = pKV + (size_t)NC * 32 * 4096;

    hipLaunchKernelGGL(k_phase1, dim3(32 * NC), dim3(256), 0, stream, K, V, pKV, pKs, NC, sLen);
    switch (NC) {
        case 32: hipLaunchKernelGGL(k_reduceT<32>, dim3(256), dim3(128), 0, stream, pKV, pKs, KVf, Ksf); break;
        case 16: hipLaunchKernelGGL(k_reduceT<16>, dim3(256), dim3(128), 0, stream, pKV, pKs, KVf, Ksf); break;
        case 8:  hipLaunchKernelGGL(k_reduceT<8>,  dim3(256), dim3(128), 0, stream, pKV, pKs, KVf, Ksf); break;
        default: hipLaunchKernelGGL(k_reduceG, dim3(256), dim3(128), 0, stream, pKV, pKs, KVf, Ksf, NC); break;
    }
    hipLaunchKernelGGL(k_phase2, dim3(512), dim3(256), 0, stream, Q, KVf, Ksf, out);
}

// Round 5
// 55.338 us; speedup vs baseline: 3.0423x; 1.0261x over previous
//
#include <hip/hip_runtime.h>
#include <math.h>

#define SEQ 4096
#define NH  8
#define DIM 64
// 32 (n,h) pairs total: n=4, h=8

__device__ __forceinline__ float elu1(float x) {
    // jax.nn.elu(x)+1 = x+1 (x>0) else exp(x)
    return x > 0.0f ? x + 1.0f : __expf(x);
}

// ---------------- Phase 1: partial KV (64x64) + partial Ksum per (n,h,chunk) ----------------
// 256 thr = 4 waves. Each wave owns 4 of the 16 staged s-rows (K-split),
// each lane an 8x8 (d,v) tile -> 64 B LDS per 64 fma = 1.0 B/fma (was 2.0).
// Cross-wave acc tree-reduction via 16KB LDS buffer at block end.
__global__ __launch_bounds__(256) void k_phase1(const float* __restrict__ Kin,
                                                const float* __restrict__ Vin,
                                                float* __restrict__ pKV,
                                                float* __restrict__ pKs,
                                                int NC, int sLen) {
    const int nh = blockIdx.x / NC;
    const int ck = blockIdx.x % NC;
    const int n  = nh >> 3, h = nh & 7;
    const int t  = threadIdx.x;
    const int r  = t >> 4;          // staging row 0..15
    const int c  = (t & 15) * 4;    // staging col (x4)
    const int wv   = t >> 6;        // wave 0..3
    const int lane = t & 63;
    const int d0 = (lane >> 3) * 8; // owned d block (8 rows of KV)
    const int v0 = (lane & 7) * 8;  // owned v block (8 cols)

    __shared__ __align__(16) float kf[2][16][64];   // 8 KB
    __shared__ __align__(16) float vv[2][16][64];   // 8 KB
    __shared__ __align__(16) float sred[4096];      // 16 KB cross-wave reduce

    float acc[8][8];
#pragma unroll
    for (int i = 0; i < 8; i++)
#pragma unroll
        for (int j = 0; j < 8; j++) acc[i][j] = 0.0f;
    float ks[4] = {0.0f, 0.0f, 0.0f, 0.0f};

    const int s0 = ck * sLen;
    const int iters = sLen >> 4;

    // prologue: stage tile 0 into buffer 0
    {
        const size_t g = ((size_t)(n * SEQ + s0 + r) * NH + h) * DIM + c;
        float4 k4 = *(const float4*)(Kin + g);
        float4 v4 = *(const float4*)(Vin + g);
        float4 f4;
        f4.x = elu1(k4.x); f4.y = elu1(k4.y); f4.z = elu1(k4.z); f4.w = elu1(k4.w);
        ks[0] += f4.x; ks[1] += f4.y; ks[2] += f4.z; ks[3] += f4.w;
        *(float4*)&kf[0][r][c] = f4;
        *(float4*)&vv[0][r][c] = v4;
    }

    for (int it = 0; it < iters; ++it) {
        __syncthreads();                 // tile `it` visible; prior-iter reads done
        const int cur = it & 1;
        float4 k4, v4;
        const bool more = (it + 1 < iters);
        if (more) {                      // issue next tile's loads early
            const size_t g = ((size_t)(n * SEQ + s0 + (it + 1) * 16 + r) * NH + h) * DIM + c;
            k4 = *(const float4*)(Kin + g);
            v4 = *(const float4*)(Vin + g);
        }
        // this wave's 4 s-rows
#pragma unroll
        for (int ssi = 0; ssi < 4; ++ssi) {
            const int ss = wv * 4 + ssi;
            float4 a0 = *(const float4*)&kf[cur][ss][d0];
            float4 a1 = *(const float4*)&kf[cur][ss][d0 + 4];
            float4 b0 = *(const float4*)&vv[cur][ss][v0];
            float4 b1 = *(const float4*)&vv[cur][ss][v0 + 4];
            float a[8] = {a0.x, a0.y, a0.z, a0.w, a1.x, a1.y, a1.z, a1.w};
            float b[8] = {b0.x, b0.y, b0.z, b0.w, b1.x, b1.y, b1.z, b1.w};
#pragma unroll
            for (int i = 0; i < 8; i++)
#pragma unroll
                for (int j = 0; j < 8; j++)
                    acc[i][j] = fmaf(a[i], b[j], acc[i][j]);
        }
        if (more) {
            float4 f4;
            f4.x = elu1(k4.x); f4.y = elu1(k4.y); f4.z = elu1(k4.z); f4.w = elu1(k4.w);
            ks[0] += f4.x; ks[1] += f4.y; ks[2] += f4.z; ks[3] += f4.w;
            *(float4*)&kf[cur ^ 1][r][c] = f4;
            *(float4*)&vv[cur ^ 1][r][c] = v4;
        }
    }

    // cross-wave acc reduction: w3 -> w2 -> w1 -> w0 through sred (transposed
    // layout elem*64+lane: banks = lane%32, 2 lanes/bank = free)
#pragma unroll
    for (int src = 3; src >= 1; --src) {
        __syncthreads();
        if (wv == src) {
#pragma unroll
            for (int i = 0; i < 8; i++)
#pragma unroll
                for (int j = 0; j < 8; j++) sred[(i * 8 + j) * 64 + lane] = acc[i][j];
        }
        __syncthreads();
        if (wv == src - 1) {
#pragma unroll
            for (int i = 0; i < 8; i++)
#pragma unroll
                for (int j = 0; j < 8; j++) acc[i][j] += sred[(i * 8 + j) * 64 + lane];
        }
    }

    // wave0 stores partial KV: pKV[(ck*32+nh)][d][v]
    if (wv == 0) {
        float* dst = pKV + ((size_t)ck * 32 + nh) * 4096;
#pragma unroll
        for (int i = 0; i < 8; i++) {
            float4 oa, ob;
            oa.x = acc[i][0]; oa.y = acc[i][1]; oa.z = acc[i][2]; oa.w = acc[i][3];
            ob.x = acc[i][4]; ob.y = acc[i][5]; ob.z = acc[i][6]; ob.w = acc[i][7];
            *(float4*)(dst + (d0 + i) * 64 + v0)     = oa;
            *(float4*)(dst + (d0 + i) * 64 + v0 + 4) = ob;
        }
    }

    // Ksum reduce via LDS (reuse kf[0]; guarded by barrier)
    __syncthreads();
    *(float4*)&kf[0][r][c] = make_float4(ks[0], ks[1], ks[2], ks[3]);
    __syncthreads();
    if (t < 64) {
        float s = 0.0f;
#pragma unroll
        for (int rr = 0; rr < 16; ++rr) s += kf[0][rr][t];
        pKs[((size_t)ck * 32 + nh) * 64 + t] = s;
    }
}

// ---------------- Reduce partials -> final KV, Ksum ----------------
template <int NC>
__global__ __launch_bounds__(128) void k_reduceT(const float* __restrict__ pKV,
                                                 const float* __restrict__ pKs,
                                                 float* __restrict__ KVf,
                                                 float* __restrict__ Ksf) {
    const int gid = blockIdx.x * 128 + threadIdx.x;   // 0..32767, one float4 each
    const float4* p4 = (const float4*)pKV;
    float4 s = make_float4(0.f, 0.f, 0.f, 0.f);
#pragma unroll
    for (int c = 0; c < NC; ++c) {
        float4 v = p4[(size_t)c * 32768 + gid];
        s.x += v.x; s.y += v.y; s.z += v.z; s.w += v.w;
    }
    ((float4*)KVf)[gid] = s;
    if (gid < 2048) {
        float ss = 0.0f;
#pragma unroll
        for (int c = 0; c < NC; ++c) ss += pKs[(size_t)c * 2048 + gid];
        Ksf[gid] = ss;
    }
}

__global__ __launch_bounds__(128) void k_reduceG(const float* __restrict__ pKV,
                                                 const float* __restrict__ pKs,
                                                 float* __restrict__ KVf,
                                                 float* __restrict__ Ksf, int NC) {
    const int gid = blockIdx.x * 128 + threadIdx.x;
    const float4* p4 = (const float4*)pKV;
    float4 s = make_float4(0.f, 0.f, 0.f, 0.f);
    for (int c = 0; c < NC; ++c) {
        float4 v = p4[(size_t)c * 32768 + gid];
        s.x += v.x; s.y += v.y; s.z += v.z; s.w += v.w;
    }
    ((float4*)KVf)[gid] = s;
    if (gid < 2048) {
        float ss = 0.0f;
        for (int c = 0; c < NC; ++c) ss += pKs[(size_t)c * 2048 + gid];
        Ksf[gid] = ss;
    }
}

// ---------------- Phase 2: register-tiled GEMM, out[l,v] = (Qf.KV[:,v]) / (Qf.Ks + eps) ----------------
// 512 blocks (32 nh x 16 tiles of 256 rows), 256 threads, 8x8 per-thread tile.
// Qt chunked to 16 d-rows (16KB) -> total LDS 32.3KB -> 4 blocks/CU (was 2-3).
// Swizzle: col = row ^ s, s = (d%16) & 12 -> writes and b128 reads <=2-way.
__global__ __launch_bounds__(256) void k_phase2(const float* __restrict__ Qin,
                                                const float* __restrict__ KVf,
                                                const float* __restrict__ Ksf,
                                                float* __restrict__ Out) {
    const int nh   = blockIdx.x >> 4;
    const int tile = blockIdx.x & 15;
    const int n = nh >> 3, h = nh & 7;
    const int t = threadIdx.x;

    __shared__ __align__(16) float Qt[16 * 256];   // 16 KB, swizzled transpose chunk
    __shared__ __align__(16) float KVs[64][64];    // 16 KB
    __shared__ float Kss[64];

    // stage KV + Ksum (coalesced; small, L2/L3-resident)
    {
        const float4* src = (const float4*)(KVf + (size_t)nh * 4096);
        float4* dst = (float4*)&KVs[0][0];
#pragma unroll
        for (int i = 0; i < 4; ++i) dst[t + 256 * i] = src[t + 256 * i];
        if (t < 64) Kss[t] = Ksf[nh * 64 + t];
    }

    const int l0 = tile * 256;
    const int r0 = (t >> 3) * 8;     // owned rows (8), 0..248
    const int v0 = (t & 7) * 8;      // owned cols (8)

    float acc[8][8];
#pragma unroll
    for (int i = 0; i < 8; i++)
#pragma unroll
        for (int j = 0; j < 8; j++) acc[i][j] = 0.0f;
    float p[8] = {0.f, 0.f, 0.f, 0.f, 0.f, 0.f, 0.f, 0.f};

    for (int dc = 0; dc < 4; ++dc) {
        if (dc) __syncthreads();       // protect Qt before overwrite
        // stage Q chunk (16 d) transposed+swizzled: 1024 float4
#pragma unroll
        for (int i = 0; i < 4; ++i) {
            const int j   = t + 256 * i;
            const int row = j >> 2;           // 0..255
            const int dl4 = (j & 3) << 2;     // local d f4-group: 0,4,8,12
            const size_t g = ((size_t)(n * SEQ + l0 + row) * NH + h) * DIM + dc * 16 + dl4;
            float4 q4 = *(const float4*)(Qin + g);
            const int col = row ^ dl4;
            Qt[(dl4 + 0) * 256 + col] = elu1(q4.x);
            Qt[(dl4 + 1) * 256 + col] = elu1(q4.y);
            Qt[(dl4 + 2) * 256 + col] = elu1(q4.z);
            Qt[(dl4 + 3) * 256 + col] = elu1(q4.w);
        }
        __syncthreads();

#pragma unroll 2
        for (int dl = 0; dl < 16; ++dl) {
            const int d = dc * 16 + dl;
            const int s = dl & 12;
            float4 qa = *(const float4*)&Qt[dl * 256 + (r0 ^ s)];
            float4 qb = *(const float4*)&Qt[dl * 256 + ((r0 + 4) ^ s)];
            float4 ka = *(const float4*)&KVs[d][v0];
            float4 kb = *(const float4*)&KVs[d][v0 + 4];
            const float ksd = Kss[d];
            float q[8]  = {qa.x, qa.y, qa.z, qa.w, qb.x, qb.y, qb.z, qb.w};
            float kv[8] = {ka.x, ka.y, ka.z, ka.w, kb.x, kb.y, kb.z, kb.w};
#pragma unroll
            for (int i = 0; i < 8; ++i) {
                p[i] = fmaf(q[i], ksd, p[i]);
#pragma unroll
                for (int jj = 0; jj < 8; ++jj)
                    acc[i][jj] = fmaf(q[i], kv[jj], acc[i][jj]);
            }
        }
    }

    // epilogue: scale by 1/(p+eps), float4 stores
#pragma unroll
    for (int i = 0; i < 8; ++i) {
        const float z = 1.0f / (p[i] + 1e-6f);
        const int l = l0 + r0 + i;
        float* o = Out + ((size_t)(n * SEQ + l) * NH + h) * DIM + v0;
        float4 oa, ob;
        oa.x = acc[i][0] * z; oa.y = acc[i][1] * z; oa.z = acc[i][2] * z; oa.w = acc[i][3] * z;
        ob.x = acc[i][4] * z; ob.y = acc[i][5] * z; ob.z = acc[i][6] * z; ob.w = acc[i][7] * z;
        *(float4*)(o)     = oa;
        *(float4*)(o + 4) = ob;
    }
}

extern "C" void kernel_launch(void* const* d_in, const int* in_sizes, int n_in,
                              void* d_out, int out_size, void* d_ws, size_t ws_size,
                              hipStream_t stream) {
    const float* Q = (const float*)d_in[0];
    const float* K = (const float*)d_in[1];
    const float* V = (const float*)d_in[2];
    float* out = (float*)d_out;

    // ws layout: [KVf 32*4096][Ksf 32*64][pKV NC*32*4096][pKs NC*32*64]
    int NC = 16;  // 512 phase1 blocks (2/CU), pKV round-trip halved vs 32
    const size_t unit = 133120ull * 4ull; // (4096+64)*32 floats in bytes
    while (NC > 1 && (size_t)(NC + 1) * unit > ws_size) NC >>= 1;
    const int sLen = SEQ / NC;

    float* KVf = (float*)d_ws;
    float* Ksf = KVf + 32 * 4096;
    float* pKV = Ksf + 32 * 64;
    float* pKs = pKV + (size_t)NC * 32 * 4096;

    hipLaunchKernelGGL(k_phase1, dim3(32 * NC), dim3(256), 0, stream, K, V, pKV, pKs, NC, sLen);
    switch (NC) {
        case 32: hipLaunchKernelGGL(k_reduceT<32>, dim3(256), dim3(128), 0, stream, pKV, pKs, KVf, Ksf); break;
        case 16: hipLaunchKernelGGL(k_reduceT<16>, dim3(256), dim3(128), 0, stream, pKV, pKs, KVf, Ksf); break;
        case 8:  hipLaunchKernelGGL(k_reduceT<8>,  dim3(256), dim3(128), 0, stream, pKV, pKs, KVf, Ksf); break;
        default: hipLaunchKernelGGL(k_reduceG, dim3(256), dim3(128), 0, stream, pKV, pKs, KVf, Ksf, NC); break;
    }
    hipLaunchKernelGGL(k_phase2, dim3(512), dim3(256), 0, stream, Q, KVf, Ksf, out);
}